// Round 2
// baseline (1502.135 us; speedup 1.0000x reference)
//
#include <hip/hip_runtime.h>
#include <hip/hip_bf16.h>

typedef unsigned int u32;

#define NPTS 120000
#define N1PTS 15000
#define NCLSS 17

static inline int cdiv(int a, int b) { return (a + b - 1) / b; }

// ---------------- sparse conv (gather-GEMM) + fused bn stats ----------------
// out[p][o] = sum_k sum_c src[nbr[p,k]][c] * W[k*CIN*COUT + c*COUT + o]
// stats[0..31] += column sums, stats[32..63] += column sums of squares
template<int K, int CIN, int COUT, bool IDENT>
__global__ __launch_bounds__(256) void conv_kernel(
    const float* __restrict__ src, const int* __restrict__ nbr,
    const float* __restrict__ W, float* __restrict__ out,
    float* __restrict__ stats, int M)
{
    static_assert(COUT == 32, "stats reduce assumes COUT==32");
    int p = blockIdx.x * 256 + threadIdx.x;
    float acc[COUT];
#pragma unroll
    for (int o = 0; o < COUT; ++o) acc[o] = 0.f;

    if (p < M) {
#pragma unroll 1
        for (int k = 0; k < K; ++k) {
            int idx = IDENT ? p : nbr[(size_t)p * K + k];
            if (idx >= 0) {
                const float* __restrict__ xr = src + (size_t)idx * CIN;
                float xv[CIN];
                if constexpr ((CIN % 4) == 0) {
#pragma unroll
                    for (int c = 0; c < CIN; c += 4) {
                        float4 v = *reinterpret_cast<const float4*>(xr + c);
                        xv[c] = v.x; xv[c + 1] = v.y; xv[c + 2] = v.z; xv[c + 3] = v.w;
                    }
                } else {
#pragma unroll
                    for (int c = 0; c < CIN; ++c) xv[c] = xr[c];
                }
                const float* __restrict__ wk = W + k * CIN * COUT;
#pragma unroll
                for (int c = 0; c < CIN; ++c)
#pragma unroll
                    for (int o = 0; o < COUT; ++o)
                        acc[o] = fmaf(xv[c], wk[c * COUT + o], acc[o]);
            }
        }
#pragma unroll
        for (int o = 0; o < COUT; o += 4) {
            float4 v; v.x = acc[o]; v.y = acc[o + 1]; v.z = acc[o + 2]; v.w = acc[o + 3];
            *reinterpret_cast<float4*>(out + (size_t)p * COUT + o) = v;
        }
    }

    // block-level stats reduction (all threads participate; inactive contribute 0)
    int lane = threadIdx.x & 63;
    int wid = threadIdx.x >> 6;
    float sel1 = 0.f, sel2 = 0.f;
#pragma unroll
    for (int o = 0; o < COUT; ++o) {
        float s1 = acc[o];
        float s2 = acc[o] * acc[o];
#pragma unroll
        for (int m = 1; m <= 32; m <<= 1) { s1 += __shfl_xor(s1, m, 64); s2 += __shfl_xor(s2, m, 64); }
        if (lane == o) sel1 = s1;
        if (lane == o + 32) sel2 = s2;
    }
    float val = (lane < 32) ? sel1 : sel2;
    __shared__ float red[4][64];
    red[wid][lane] = val;
    __syncthreads();
    if (wid == 0) {
        float t = red[0][lane] + red[1][lane] + red[2][lane] + red[3][lane];
        atomicAdd(&stats[lane], t);
    }
}

// ---------------- bn (training-mode batch stats) apply, in place ----------------
template<bool RELU>
__global__ __launch_bounds__(256) void bn_apply(
    float* __restrict__ buf, const float* __restrict__ stats,
    const float* __restrict__ gb, float invM, int total4)
{
    int i = blockIdx.x * 256 + threadIdx.x;
    if (i >= total4) return;
    int c0 = (i & 7) * 4;
    float4 v = reinterpret_cast<float4*>(buf)[i];
    float r[4] = { v.x, v.y, v.z, v.w };
#pragma unroll
    for (int j = 0; j < 4; ++j) {
        int c = c0 + j;
        float mu = stats[c] * invM;
        float var = fmaxf(stats[32 + c] * invM - mu * mu, 0.f);
        float a = gb[c] * rsqrtf(var + 1e-5f);
        float b = gb[32 + c] - mu * a;
        float y = fmaf(a, r[j], b);
        if (RELU) y = fmaxf(y, 0.f);
        r[j] = y;
    }
    v.x = r[0]; v.y = r[1]; v.z = r[2]; v.w = r[3];
    reinterpret_cast<float4*>(buf)[i] = v;
}

// bn+relu on u (raw) into cat[:,0:32], copy x0 into cat[:,32:64]
__global__ __launch_bounds__(256) void bnrelu_cat(
    const float* __restrict__ u, const float* __restrict__ x0,
    float* __restrict__ cat, const float* __restrict__ stats,
    const float* __restrict__ gb, float invM, int total8)
{
    int i = blockIdx.x * 256 + threadIdx.x;
    if (i >= total8) return;
    int p = i >> 3, j = i & 7;
    int c0 = j * 4;
    float4 v = *reinterpret_cast<const float4*>(u + (size_t)p * 32 + c0);
    float r[4] = { v.x, v.y, v.z, v.w };
#pragma unroll
    for (int t = 0; t < 4; ++t) {
        int c = c0 + t;
        float mu = stats[c] * invM;
        float var = fmaxf(stats[32 + c] * invM - mu * mu, 0.f);
        float a = gb[c] * rsqrtf(var + 1e-5f);
        float b = gb[32 + c] - mu * a;
        r[t] = fmaxf(fmaf(a, r[t], b), 0.f);
    }
    v.x = r[0]; v.y = r[1]; v.z = r[2]; v.w = r[3];
    *reinterpret_cast<float4*>(cat + (size_t)p * 64 + c0) = v;
    float4 w = *reinterpret_cast<const float4*>(x0 + (size_t)p * 32 + c0);
    *reinterpret_cast<float4*>(cat + (size_t)p * 64 + 32 + c0) = w;
}

// ---------------- attention ----------------
// att layout (floats): [0]=max (uint-encoded), [1]=S, [2..33]=z, [34..65]=ctx
__global__ __launch_bounds__(256) void att_logits(
    const float* __restrict__ net, const float* __restrict__ wi,
    const float* __restrict__ bi, float* __restrict__ lbuf,
    u32* __restrict__ mx, int M)
{
    int p = blockIdx.x * 256 + threadIdx.x;
    float l = -3.0e38f;
    if (p < M) {
        float s = bi[0];
#pragma unroll
        for (int c = 0; c < 32; c += 4) {
            float4 v = *reinterpret_cast<const float4*>(net + (size_t)p * 32 + c);
            s = fmaf(v.x, wi[c], s); s = fmaf(v.y, wi[c + 1], s);
            s = fmaf(v.z, wi[c + 2], s); s = fmaf(v.w, wi[c + 3], s);
        }
        lbuf[p] = s;
        l = s;
    }
#pragma unroll
    for (int m = 1; m <= 32; m <<= 1) l = fmaxf(l, __shfl_xor(l, m, 64));
    if ((threadIdx.x & 63) == 0) {
        u32 b = __float_as_uint(l);
        u32 e = (b & 0x80000000u) ? ~b : (b | 0x80000000u);
        atomicMax(mx, e);
    }
}

__global__ __launch_bounds__(256) void att_accum(
    const float* __restrict__ net, const float* __restrict__ lbuf,
    float* __restrict__ att, int M)
{
    int p = blockIdx.x * 256 + threadIdx.x;
    int lane = threadIdx.x & 63, wid = threadIdx.x >> 6;
    u32 um = __float_as_uint(att[0]);
    float mx = (um & 0x80000000u) ? __uint_as_float(um ^ 0x80000000u) : __uint_as_float(~um);
    float w = 0.f;
    float nv[32];
#pragma unroll
    for (int c = 0; c < 32; ++c) nv[c] = 0.f;
    if (p < M) {
        w = expf(lbuf[p] - mx);
#pragma unroll
        for (int c = 0; c < 32; c += 4) {
            float4 v = *reinterpret_cast<const float4*>(net + (size_t)p * 32 + c);
            nv[c] = v.x; nv[c + 1] = v.y; nv[c + 2] = v.z; nv[c + 3] = v.w;
        }
    }
    float sel = 0.f;
#pragma unroll
    for (int c = 0; c < 32; ++c) {
        float s = w * nv[c];
#pragma unroll
        for (int m = 1; m <= 32; m <<= 1) s += __shfl_xor(s, m, 64);
        if (lane == c) sel = s;
    }
    {
        float s = w;
#pragma unroll
        for (int m = 1; m <= 32; m <<= 1) s += __shfl_xor(s, m, 64);
        if (lane == 32) sel = s;
    }
    __shared__ float red[4][33];
    if (lane < 33) red[wid][lane] = sel;
    __syncthreads();
    if (wid == 0 && lane < 33) {
        float t = red[0][lane] + red[1][lane] + red[2][lane] + red[3][lane];
        atomicAdd(lane < 32 ? &att[2 + lane] : &att[1], t);
    }
}

__global__ void att_ctx_k(const float* __restrict__ wk, const float* __restrict__ bk,
                          float* __restrict__ att)
{
    int o = threadIdx.x;
    if (o >= 32) return;
    float invS = 1.0f / att[1];
    float s = bk[o];
#pragma unroll
    for (int c = 0; c < 32; ++c) s = fmaf(att[2 + c] * invS, wk[c * 32 + o], s);
    att[34 + o] = s;
}

// v = (net@wv+bv)*ctx ; r = relu(v@wo + bo + d)
__global__ __launch_bounds__(256) void att_out_res(
    const float* __restrict__ net, const float* __restrict__ d,
    const float* __restrict__ wv, const float* __restrict__ bv,
    const float* __restrict__ wo, const float* __restrict__ bo,
    const float* __restrict__ att, float* __restrict__ r, int M)
{
    int p = blockIdx.x * 256 + threadIdx.x;
    if (p >= M) return;
    float nv[32];
#pragma unroll
    for (int c = 0; c < 32; c += 4) {
        float4 v = *reinterpret_cast<const float4*>(net + (size_t)p * 32 + c);
        nv[c] = v.x; nv[c + 1] = v.y; nv[c + 2] = v.z; nv[c + 3] = v.w;
    }
    float vv[32];
#pragma unroll
    for (int o = 0; o < 32; ++o) {
        float s = bv[o];
#pragma unroll
        for (int c = 0; c < 32; ++c) s = fmaf(nv[c], wv[c * 32 + o], s);
        vv[o] = s * att[34 + o];
    }
#pragma unroll
    for (int oo = 0; oo < 32; ++oo) {
        float s = bo[oo];
#pragma unroll
        for (int o = 0; o < 32; ++o) s = fmaf(vv[o], wo[o * 32 + oo], s);
        float rr = s + d[(size_t)p * 32 + oo];
        r[(size_t)p * 32 + oo] = fmaxf(rr, 0.f);
    }
}

// ---------------- final: y = relu(bn(net2) + bn(ds)); out = y@Wcls + bcls ----------------
__global__ __launch_bounds__(256) void final_cls(
    const float* __restrict__ net2, const float* __restrict__ dsr,
    const float* __restrict__ st7, const float* __restrict__ st8,
    const float* __restrict__ gb7, const float* __restrict__ gb8,
    const float* __restrict__ wcls, const float* __restrict__ bcls,
    float* __restrict__ outp, float invM, int M)
{
    int p = blockIdx.x * 256 + threadIdx.x;
    if (p >= M) return;
    float y[32];
#pragma unroll
    for (int c = 0; c < 32; ++c) {
        float mu1 = st7[c] * invM;
        float var1 = fmaxf(st7[32 + c] * invM - mu1 * mu1, 0.f);
        float a1 = gb7[c] * rsqrtf(var1 + 1e-5f);
        float b1 = gb7[32 + c] - mu1 * a1;
        float mu2 = st8[c] * invM;
        float var2 = fmaxf(st8[32 + c] * invM - mu2 * mu2, 0.f);
        float a2 = gb8[c] * rsqrtf(var2 + 1e-5f);
        float b2 = gb8[32 + c] - mu2 * a2;
        float t = fmaf(a1, net2[(size_t)p * 32 + c], b1) + fmaf(a2, dsr[(size_t)p * 32 + c], b2);
        y[c] = fmaxf(t, 0.f);
    }
#pragma unroll
    for (int j = 0; j < NCLSS; ++j) {
        float s = bcls[j];
#pragma unroll
        for (int c = 0; c < 32; ++c) s = fmaf(y[c], wcls[c * NCLSS + j], s);
        outp[(size_t)p * NCLSS + j] = s;
    }
}

// ---------------- host ----------------
extern "C" void kernel_launch(void* const* d_in, const int* in_sizes, int n_in,
                              void* d_out, int out_size, void* d_ws, size_t ws_size,
                              hipStream_t stream)
{
    float* ws = (float*)d_ws;

    // workspace layout (floats)
    const size_t OFF_ST = 0;                   // 9*64 stats + 66 att = 642
    const size_t OFF_A  = 704;                 // N*32
    const size_t OFF_B  = OFF_A + 3840000;     // N*32
    const size_t OFF_C  = OFF_B + 3840000;     // N1*32
    const size_t OFF_D  = OFF_C + 480000;      // N1*32
    const size_t OFF_E  = OFF_D + 480000;      // N1*32
    const size_t OFF_L  = OFF_E + 480000;      // N1 logits (pad 15040)
    const size_t OFF_F  = OFF_L + 15040;       // N*64 (cat); first N*32 reused as net2 (G)

    float* A = ws + OFF_A;
    float* B = ws + OFF_B;
    float* C = ws + OFF_C;
    float* D = ws + OFF_D;
    float* E = ws + OFF_E;
    float* L = ws + OFF_L;
    float* F = ws + OFF_F;
    float* G = F;                              // fuse2 output overwrites cat (dead by then)
    float* ST = ws + OFF_ST;
    float* ATT = ST + 576;

    // inputs (fp32 per reference dtypes)
    const float* X        = (const float*)d_in[0];
    const float* Wstem0   = (const float*)d_in[1];
    const float* gb_stem0 = (const float*)d_in[2];
    const float* Wstem1   = (const float*)d_in[3];
    const float* gb_stem1 = (const float*)d_in[4];
    const float* Wdown    = (const float*)d_in[5];
    const float* gb_down  = (const float*)d_in[6];
    const float* Wres1    = (const float*)d_in[7];
    const float* gb_res1  = (const float*)d_in[8];
    const float* Wres2    = (const float*)d_in[9];
    const float* gb_res2  = (const float*)d_in[10];
    const float* wi = (const float*)d_in[11];
    const float* bi = (const float*)d_in[12];
    const float* wk = (const float*)d_in[13];
    const float* bk = (const float*)d_in[14];
    const float* wv = (const float*)d_in[15];
    const float* bv = (const float*)d_in[16];
    const float* wo = (const float*)d_in[17];
    const float* bo = (const float*)d_in[18];
    const float* Wup      = (const float*)d_in[19];
    const float* gb_up    = (const float*)d_in[20];
    const float* Wfuse1   = (const float*)d_in[21];
    const float* gb_fuse1 = (const float*)d_in[22];
    const float* Wfuse2   = (const float*)d_in[23];
    const float* gb_fuse2 = (const float*)d_in[24];
    const float* Wds      = (const float*)d_in[25];
    const float* gb_ds    = (const float*)d_in[26];
    const float* Wcls     = (const float*)d_in[27];
    const float* bcls     = (const float*)d_in[28];

    const int* nbr0     = (const int*)d_in[29];
    const int* nbr_down = (const int*)d_in[30];
    const int* nbr1     = (const int*)d_in[31];
    const int* nbr_up   = (const int*)d_in[32];

    const float invN  = 1.0f / (float)NPTS;
    const float invN1 = 1.0f / (float)N1PTS;

    // zero stats + att accumulators
    hipMemsetAsync((void*)ST, 0, 642 * sizeof(float), stream);

    const int gN = cdiv(NPTS, 256);    // 469
    const int gN1 = cdiv(N1PTS, 256);  // 59
    const int gBN = cdiv(NPTS * 32 / 4, 256);   // 3750
    const int gBN1 = cdiv(N1PTS * 32 / 4, 256); // 469

    // stem
    hipLaunchKernelGGL((conv_kernel<27, 3, 32, false>), dim3(gN), dim3(256), 0, stream,
                       X, nbr0, Wstem0, A, ST + 0 * 64, NPTS);
    hipLaunchKernelGGL((bn_apply<true>), dim3(gBN), dim3(256), 0, stream,
                       A, ST + 0 * 64, gb_stem0, invN, NPTS * 8);
    hipLaunchKernelGGL((conv_kernel<27, 32, 32, false>), dim3(gN), dim3(256), 0, stream,
                       A, nbr0, Wstem1, B, ST + 1 * 64, NPTS);
    hipLaunchKernelGGL((bn_apply<true>), dim3(gBN), dim3(256), 0, stream,
                       B, ST + 1 * 64, gb_stem1, invN, NPTS * 8);   // B = x0

    // downsample
    hipLaunchKernelGGL((conv_kernel<8, 32, 32, false>), dim3(gN1), dim3(256), 0, stream,
                       B, nbr_down, Wdown, C, ST + 2 * 64, N1PTS);
    hipLaunchKernelGGL((bn_apply<true>), dim3(gBN1), dim3(256), 0, stream,
                       C, ST + 2 * 64, gb_down, invN1, N1PTS * 8);  // C = d

    // residual block convs
    hipLaunchKernelGGL((conv_kernel<27, 32, 32, false>), dim3(gN1), dim3(256), 0, stream,
                       C, nbr1, Wres1, D, ST + 3 * 64, N1PTS);
    hipLaunchKernelGGL((bn_apply<true>), dim3(gBN1), dim3(256), 0, stream,
                       D, ST + 3 * 64, gb_res1, invN1, N1PTS * 8);
    hipLaunchKernelGGL((conv_kernel<27, 32, 32, false>), dim3(gN1), dim3(256), 0, stream,
                       D, nbr1, Wres2, E, ST + 4 * 64, N1PTS);
    hipLaunchKernelGGL((bn_apply<false>), dim3(gBN1), dim3(256), 0, stream,
                       E, ST + 4 * 64, gb_res2, invN1, N1PTS * 8);  // E = net

    // attention + residual add (writes r into D)
    hipLaunchKernelGGL(att_logits, dim3(gN1), dim3(256), 0, stream,
                       E, wi, bi, L, (u32*)ATT, N1PTS);
    hipLaunchKernelGGL(att_accum, dim3(gN1), dim3(256), 0, stream, E, L, ATT, N1PTS);
    hipLaunchKernelGGL(att_ctx_k, dim3(1), dim3(64), 0, stream, wk, bk, ATT);
    hipLaunchKernelGGL(att_out_res, dim3(gN1), dim3(256), 0, stream,
                       E, C, wv, bv, wo, bo, ATT, D, N1PTS);        // D = r

    // upsample + cat
    hipLaunchKernelGGL((conv_kernel<8, 32, 32, false>), dim3(gN), dim3(256), 0, stream,
                       D, nbr_up, Wup, A, ST + 5 * 64, NPTS);
    hipLaunchKernelGGL(bnrelu_cat, dim3(gBN), dim3(256), 0, stream,
                       A, B, F, ST + 5 * 64, gb_up, invN, NPTS * 8); // F = cat

    // fuse residual block: ds first (frees F for reuse), then fuse1/fuse2
    hipLaunchKernelGGL((conv_kernel<1, 64, 32, true>), dim3(gN), dim3(256), 0, stream,
                       F, (const int*)nullptr, Wds, B, ST + 8 * 64, NPTS); // B = ds raw
    hipLaunchKernelGGL((conv_kernel<27, 64, 32, false>), dim3(gN), dim3(256), 0, stream,
                       F, nbr0, Wfuse1, A, ST + 6 * 64, NPTS);
    hipLaunchKernelGGL((bn_apply<true>), dim3(gBN), dim3(256), 0, stream,
                       A, ST + 6 * 64, gb_fuse1, invN, NPTS * 8);
    hipLaunchKernelGGL((conv_kernel<27, 32, 32, false>), dim3(gN), dim3(256), 0, stream,
                       A, nbr0, Wfuse2, G, ST + 7 * 64, NPTS);       // G = net2 raw (overwrites cat)

    // final fuse + classifier
    hipLaunchKernelGGL(final_cls, dim3(gN), dim3(256), 0, stream,
                       G, B, ST + 7 * 64, ST + 8 * 64, gb_fuse2, gb_ds,
                       Wcls, bcls, (float*)d_out, invN, NPTS);
}